// Round 11
// baseline (182.764 us; speedup 1.0000x reference)
//
#include <hip/hip_runtime.h>
#include <math.h>

// Fixed problem shapes: B=1, C=3, V=9, K=8, H=W=512
constexpr int N    = 512;
constexpr int LOGN = 9;
constexpr int NN   = N * N;                       // 262144
constexpr int CCH  = 3;
constexpr int KK   = 8;
constexpr int VV   = 9;
constexpr int FHALF = N * (N / 2) + (N / 2 + 1);  // 131329
constexpr int NS   = 257;                         // half-spectrum lines per image
constexpr int RW   = 544;                         // buf row width (= FFT scratch size)
constexpr float PI_F = 3.14159265358979323846f;

__device__ __forceinline__ float2 cmulf(float2 a, float2 b) {
    return make_float2(a.x * b.x - a.y * b.y, a.x * b.y + a.y * b.x);
}
__device__ __forceinline__ float2 cadd(float2 a, float2 b) { return make_float2(a.x + b.x, a.y + b.y); }
__device__ __forceinline__ float2 csub(float2 a, float2 b) { return make_float2(a.x - b.x, a.y - b.y); }

template<int SG>
__device__ __forceinline__ float2 cmuli(float2 z) {
    return (SG < 0) ? make_float2(z.y, -z.x) : make_float2(-z.y, z.x);
}

// 8-point DFT, natural order in/out. SG=-1 forward, +1 inverse.
template<int SG>
__device__ __forceinline__ void dft8(float2 x[8]) {
    const float c = 0.70710678118654752440f;
    float2 a0 = cadd(x[0], x[4]), a1 = cadd(x[1], x[5]);
    float2 a2 = cadd(x[2], x[6]), a3 = cadd(x[3], x[7]);
    float2 d0 = csub(x[0], x[4]), d1 = csub(x[1], x[5]);
    float2 d2 = csub(x[2], x[6]), d3 = csub(x[3], x[7]);
    float2 b0 = d0;
    float2 b1 = cmulf(d1, make_float2(c, (float)SG * c));
    float2 b2 = cmuli<SG>(d2);
    float2 b3 = cmulf(d3, make_float2(-c, (float)SG * c));
    float2 aa0 = cadd(a0, a2), aa1 = cadd(a1, a3);
    float2 ab0 = csub(a0, a2), ab1 = cmuli<SG>(csub(a1, a3));
    float2 ba0 = cadd(b0, b2), ba1 = cadd(b1, b3);
    float2 bb0 = csub(b0, b2), bb1 = cmuli<SG>(csub(b1, b3));
    x[0] = cadd(aa0, aa1); x[4] = csub(aa0, aa1);
    x[2] = cadd(ab0, ab1); x[6] = csub(ab0, ab1);
    x[1] = cadd(ba0, ba1); x[5] = csub(ba0, ba1);
    x[3] = cadd(bb0, bb1); x[7] = csub(bb0, bb1);
}

__device__ __forceinline__ void twiddle8(float2 v[8], float base) {
    float sn, cs;
    __sincosf(base, &sn, &cs);
    float2 w1 = make_float2(cs, sn);
    float2 wk = w1;
    v[1] = cmulf(v[1], wk);
    #pragma unroll
    for (int k = 2; k < 8; ++k) { wk = cmulf(wk, w1); v[k] = cmulf(v[k], wk); }
}

// Wave-level 512-pt FFT, radix-8^3 (verified round 6). One wave, 8 cx/lane.
// In: v[e]=x[t+64e]. Out: v[k0]=X[(t>>3)+8*(t&7)+64*k0]. Scratch: 544 idx slots.
template<int SG>
__device__ __forceinline__ void wave_fft512(float2 v[8], float* sre, float* sim,
                                            int t, int stride, int off) {
    int t1 = t >> 3, t0 = t & 7;
    dft8<SG>(v);
    twiddle8(v, (float)SG * (2.0f * PI_F / 512.0f) * (float)t);
    #pragma unroll
    for (int k = 0; k < 8; ++k) {
        int a = (68 * k + 8 * t1 + t0) * stride + off;
        sre[a] = v[k].x; sim[a] = v[k].y;
    }
    #pragma unroll
    for (int n = 0; n < 8; ++n) {
        int a = (68 * t1 + 8 * n + t0) * stride + off;
        v[n] = make_float2(sre[a], sim[a]);
    }
    dft8<SG>(v);
    twiddle8(v, (float)SG * (2.0f * PI_F / 64.0f) * (float)t0);
    #pragma unroll
    for (int k = 0; k < 8; ++k) {
        int a = (68 * t0 + 8 * k + t1) * stride + off;
        sre[a] = v[k].x; sim[a] = v[k].y;
    }
    #pragma unroll
    for (int n = 0; n < 8; ++n) {
        int a = (68 * n + 8 * t0 + t1) * stride + off;
        v[n] = make_float2(sre[a], sim[a]);
    }
    dft8<SG>(v);
}

// float2-scratch variant: identical math, but exchanges use ds_*_b64
// (16 writes + 16 reads per exchange pair instead of 64 b32 ops).
// All four address patterns map exactly 4 lanes per 8B bank-pair (the b64
// hardware minimum) -> conflict-free.
template<int SG>
__device__ __forceinline__ void wave_fft512_c(float2 v[8], float2* s, int t) {
    int t1 = t >> 3, t0 = t & 7;
    dft8<SG>(v);
    twiddle8(v, (float)SG * (2.0f * PI_F / 512.0f) * (float)t);
    #pragma unroll
    for (int k = 0; k < 8; ++k) s[68 * k + 8 * t1 + t0] = v[k];
    #pragma unroll
    for (int n = 0; n < 8; ++n) v[n] = s[68 * t1 + 8 * n + t0];
    dft8<SG>(v);
    twiddle8(v, (float)SG * (2.0f * PI_F / 64.0f) * (float)t0);
    #pragma unroll
    for (int k = 0; k < 8; ++k) s[68 * t0 + 8 * k + t1] = v[k];
    #pragma unroll
    for (int n = 0; n < 8; ++n) v[n] = s[68 * n + 8 * t0 + t1];
    dft8<SG>(v);
}

// Packed r2c rows, TRANSPOSED output: each wave FFTs TWO real rows as ONE
// complex FFT, splits via Hermitian symmetry, then the block transposes its
// 8 rows x 257 half-spectrum cols in LDS and stores column-major:
// outT[img][s][row], s = (p==0) ? 256 : p-256 for p in {0} U [256,511].
// LDS: FFT scratch (4x544 re/im) aliased with the 257x9-padded tile.
__global__ __launch_bounds__(256) void k_fft_r2c_rows_pack_T(const float* __restrict__ inx,
                                                             const float* __restrict__ iny,
                                                             int nximg,
                                                             float2* __restrict__ outT) {
    __shared__ float ure[2313];       // max(4*544, 257*9) = 2313
    __shared__ float uim[2313];
    int w = threadIdx.x >> 6, t = threadIdx.x & 63;
    int blk = blockIdx.x;             // 64 blocks per image, 8 rows per block
    int img = blk >> 6;
    int rowbase = (blk & 63) << 3;
    long long row0 = (long long)blk * 8 + 2 * w;   // global row (pairs never straddle)
    long long xrows = (long long)nximg * N;
    const float* src0 = (row0 < xrows) ? (inx + row0 * N)
                                       : (iny + (row0 - xrows) * N);
    const float* src1 = src0 + N;
    float* sre = ure + w * 544;
    float* sim = uim + w * 544;
    float2 v[8];
    #pragma unroll
    for (int e = 0; e < 8; ++e) v[e] = make_float2(src0[t + 64 * e], src1[t + 64 * e]);
    wave_fft512<-1>(v, sre, sim, t, 1, 0);
    int kb = (t >> 3) + 8 * (t & 7);
    #pragma unroll
    for (int k0 = 0; k0 < 8; ++k0) {          // full spectrum for mirror reads
        int p = kb + 64 * k0;
        sre[p] = v[k0].x; sim[p] = v[k0].y;
    }
    float2 r0v[4], r1v[4];
    #pragma unroll
    for (int k0 = 4; k0 < 8; ++k0) {
        int p  = kb + 64 * k0;                // 256..511
        int mp = 512 - p;                     // 1..256
        float zmx = sre[mp], zmy = sim[mp];
        float2 Zp = v[k0];
        r0v[k0 - 4] = make_float2(0.5f * (Zp.x + zmx), 0.5f * (Zp.y - zmy));
        r1v[k0 - 4] = make_float2(0.5f * (Zp.y + zmy), 0.5f * (zmx - Zp.x));
    }
    float2 z0 = v[0];                          // lane 0 holds X[0]
    __syncthreads();                           // scratch reads done; alias as tile
    #pragma unroll
    for (int k0 = 0; k0 < 4; ++k0) {
        int s = kb + 64 * k0;                  // p-256 in [0,255]
        ure[s * 9 + 2 * w]     = r0v[k0].x; uim[s * 9 + 2 * w]     = r0v[k0].y;
        ure[s * 9 + 2 * w + 1] = r1v[k0].x; uim[s * 9 + 2 * w + 1] = r1v[k0].y;
    }
    if (t == 0) {                              // p = 0 -> slot 256
        ure[256 * 9 + 2 * w]     = z0.x; uim[256 * 9 + 2 * w]     = 0.0f;
        ure[256 * 9 + 2 * w + 1] = z0.y; uim[256 * 9 + 2 * w + 1] = 0.0f;
    }
    __syncthreads();
    float2* dst = outT + (long long)img * ((long long)NS * N);
    int tt = threadIdx.x;
    int r2 = (tt & 3) << 1;                    // even row-pair -> float4 store
    #pragma unroll
    for (int j = 0; j < 4; ++j) {
        int s = j * 64 + (tt >> 2);
        *(float4*)&dst[s * N + rowbase + r2] =
            make_float4(ure[s * 9 + r2],     uim[s * 9 + r2],
                        ure[s * 9 + r2 + 1], uim[s * 9 + r2 + 1]);
    }
    if (tt < 4) {
        int r2b = tt << 1;
        *(float4*)&dst[256 * N + rowbase + r2b] =
            make_float4(ure[256 * 9 + r2b],     uim[256 * 9 + r2b],
                        ure[256 * 9 + r2b + 1], uim[256 * 9 + r2b + 1]);
    }
}

// Fallback-only: full r2c rows.
__global__ __launch_bounds__(256) void k_fft_r2c_rows(const float* __restrict__ in,
                                                      float2* __restrict__ out) {
    __shared__ float sre[4][544];
    __shared__ float sim[4][544];
    int w = threadIdx.x >> 6, t = threadIdx.x & 63;
    long long grow = (long long)blockIdx.x * 4 + w;
    const float* src = in + grow * N;
    float2 v[8];
    #pragma unroll
    for (int e = 0; e < 8; ++e) v[e] = make_float2(src[t + 64 * e], 0.0f);
    wave_fft512<-1>(v, sre[w], sim[w], t, 1, 0);
    float2* dst = out + grow * N;
    int kb = (t >> 3) + 8 * (t & 7);
    #pragma unroll
    for (int k0 = 0; k0 < 8; ++k0) dst[kb + 64 * k0] = v[k0];
}

// Fallback-only: in-place row FFT with r<->r^256 swap; lex/sex in units of 64.
template<int SG>
__global__ __launch_bounds__(256) void k_fft_pairswap(float2* __restrict__ data,
                                                      float scale, int lex, int sex) {
    __shared__ float sre[4][544];
    __shared__ float sim[4][544];
    int w = threadIdx.x >> 6, t = threadIdx.x & 63;
    int b = blockIdx.x;
    long long imgBase = (long long)(b >> 7) * NN;
    int pa = (b & 127) << 1;
    int rowg = pa + (w & 1) + ((w >> 1) << 8);
    const float2* src = data + imgBase + (long long)rowg * N;
    float2 v[8];
    #pragma unroll
    for (int e = 0; e < 8; ++e) v[e] = src[t + 64 * (e ^ lex)];
    __syncthreads();
    wave_fft512<SG>(v, sre[w], sim[w], t, 1, 0);
    float2* dst = data + imgBase + (long long)(rowg ^ 256) * N;
    int kb = (t >> 3) + 8 * (t & 7);
    #pragma unroll
    for (int k0 = 0; k0 < 8; ++k0) {
        float2 z = v[k0];
        dst[kb + 64 * (k0 ^ sex)] = make_float2(z.x * scale, z.y * scale);
    }
}

// ---- solve helpers (arithmetic verbatim from the verified k_solve) ----
__device__ __forceinline__ void accum_pair(float2 bacc[KK], float tr[KK], float s,
                                           float d0, float dlt, float2 Yp, float2 Yn) {
    float2 Sp = make_float2(Yp.x + Yn.x, Yp.y + Yn.y);
    float2 Dm = make_float2(Yp.x - Yn.x, Yp.y - Yn.y);
    float sn, cs;
    __sincosf(s * d0, &sn, &cs);  float2 p = make_float2(cs, sn);
    __sincosf(s * dlt, &sn, &cs); float2 q = make_float2(cs, sn);
    float2 w = q;
    #pragma unroll
    for (int k = 0; k < KK; ++k) {
        bacc[k].x += p.x * Sp.x + p.y * Dm.y;
        bacc[k].y += p.x * Sp.y - p.y * Dm.x;
        if (k < KK - 1) {
            p = cmulf(p, q);
            tr[k + 1] += 2.0f * w.x;
            w = cmulf(w, q);
        }
    }
}

__device__ __forceinline__ void solve_point(float2 bacc[KK], float tr[KK], float rho) {
    float diag = tr[0] + rho;
    float L[36], Li[KK];
    #pragma unroll
    for (int j = 0; j < KK; ++j) {
        float acc = diag;
        #pragma unroll
        for (int t = 0; t < j; ++t) { float l = L[(j * (j - 1)) / 2 + t]; acc -= l * l; }
        float dj = sqrtf(acc);
        float inv = 1.0f / dj;
        Li[j] = inv;
        #pragma unroll
        for (int i = j + 1; i < KK; ++i) {
            float a = tr[i - j];
            #pragma unroll
            for (int t = 0; t < j; ++t)
                a -= L[(i * (i - 1)) / 2 + t] * L[(j * (j - 1)) / 2 + t];
            L[(i * (i - 1)) / 2 + j] = a * inv;
        }
    }
    #pragma unroll
    for (int i = 0; i < KK; ++i) {
        float2 a = bacc[i];
        #pragma unroll
        for (int t = 0; t < i; ++t) {
            float l = L[(i * (i - 1)) / 2 + t];
            a.x -= l * bacc[t].x;
            a.y -= l * bacc[t].y;
        }
        bacc[i] = make_float2(a.x * Li[i], a.y * Li[i]);
    }
    #pragma unroll
    for (int i = KK - 1; i >= 0; --i) {
        float2 a = bacc[i];
        #pragma unroll
        for (int t = i + 1; t < KK; ++t) {
            float l = L[(t * (t - 1)) / 2 + i];
            a.x -= l * bacc[t].x;
            a.y -= l * bacc[t].y;
        }
        bacc[i] = make_float2(a.x * Li[i], a.y * Li[i]);
    }
}

// FUSED v5: v4 structure with float2 (b64) LDS throughout — halves the
// LDS op count of every FFT exchange and all solve-phase row accesses.
// Rows 0..8: Y spectra; rows 9..16: X spectra, then solutions.
// LDS: 17 x 544 x 8B = 74.0 KB -> 2 blocks/CU (unchanged).
__global__ __launch_bounds__(512, 4) void k_fused_solve(const float2* __restrict__ Rt,
                                                        float2* __restrict__ P,
                                                        float2* __restrict__ S0,
                                                        int nximg,
                                                        const float* __restrict__ uu,
                                                        const float* __restrict__ vvp,
                                                        const float* __restrict__ dd,
                                                        const float* __restrict__ rhop) {
    __shared__ float2 bb[KK + VV][RW];   // 74.0 KB
    int a  = blockIdx.x;                 // 0..256
    int ch = blockIdx.y;
    int t  = threadIdx.x;                // 0..511
    int w = t >> 6, lane = t & 63;
    int kb = (lane >> 3) + 8 * (lane & 7);
    const long long LN = (long long)NS * N;

    // FFT phase: issue Y[w] + X[w] loads together, FFT both (X latency hides
    // under Y's FFT).  Wave 0 additionally handles Y[8].
    {
        int ybase = nximg + ch * VV;
        float2 fvY[8], fvX[8];
        const float2* srcY = Rt + (long long)(ybase + w) * LN + (long long)a * N;
        const float2* srcX = Rt + (long long)(ch * KK + w) * LN + (long long)a * N;
        #pragma unroll
        for (int e = 0; e < 8; ++e) fvY[e] = srcY[lane + 64 * e];
        #pragma unroll
        for (int e = 0; e < 8; ++e) fvX[e] = srcX[lane + 64 * e];
        wave_fft512_c<-1>(fvY, bb[w], lane);
        #pragma unroll
        for (int k0 = 0; k0 < 8; ++k0)
            bb[w][kb + 64 * (k0 ^ 4)] = fvY[k0];         // fold the ky-roll
        wave_fft512_c<-1>(fvX, bb[9 + w], lane);
        #pragma unroll
        for (int k0 = 0; k0 < 8; ++k0)
            bb[9 + w][kb + 64 * (k0 ^ 4)] = fvX[k0];
        if (w == 0) {                                    // 17th line: Y[8]
            const float2* src8 = Rt + (long long)(ybase + 8) * LN + (long long)a * N;
            float2 fv8[8];
            #pragma unroll
            for (int e = 0; e < 8; ++e) fv8[e] = src8[lane + 64 * e];
            wave_fft512_c<-1>(fv8, bb[8], lane);
            #pragma unroll
            for (int k0 = 0; k0 < 8; ++k0)
                bb[8][kb + 64 * (k0 ^ 4)] = fv8[k0];
        }
    }
    __syncthreads();

    // Solve phase: accum RHS + Toeplitz traces, add rho*X, Cholesky solve,
    // write solutions back to rows 9..16 (thread t owns slot t).
    float rho = rhop[0];
    float d0 = dd[0], dlt = dd[1] - dd[0];
    const float C = 2.0f * PI_F / (float)N;
    float wxv = (float)(a - 256) * C;
    float wy  = (float)(t - 256) * C;
    float2 bacc[KK];
    float tr[KK];
    {
        float2 yc = bb[4][t];
        #pragma unroll
        for (int k = 0; k < KK; ++k) bacc[k] = yc;
        tr[0] = (float)VV;
        #pragma unroll
        for (int l = 1; l < KK; ++l) tr[l] = 1.0f;
    }
    #pragma unroll
    for (int j = 0; j < 4; ++j) {
        int vp = 5 + j, vn = 3 - j;
        accum_pair(bacc, tr, uu[vp] * wxv + vvp[vp] * wy, d0, dlt,
                   bb[vp][t], bb[vn][t]);
    }
    #pragma unroll
    for (int k = 0; k < KK; ++k) {
        float2 xv = bb[9 + k][t];
        bacc[k].x += rho * xv.x;
        bacc[k].y += rho * xv.y;
    }
    solve_point(bacc, tr, rho);
    #pragma unroll
    for (int k = 0; k < KK; ++k) bb[9 + k][t] = bacc[k];
    __syncthreads();

    // Inverse phase: iFFT (wave w -> k=w, row 9+w) + half-P store.
    // a==256 self-mirror folded into the read: g[idx>=257] = conj(g[512-idx]).
    {
        const float inv512 = 1.0f / 512.0f;
        int k = w;
        int row = 9 + w;
        bool selfm = (a == 256);              // uniform per block
        float2 v[8];
        #pragma unroll
        for (int e = 0; e < 8; ++e) {
            int idx = (lane + 64 * e) ^ 256;  // fold the b-roll into the load
            if (selfm && idx >= 257) {
                float2 z = bb[row][512 - idx];
                v[e] = make_float2(z.x, -z.y);
            } else {
                v[e] = bb[row][idx];
            }
        }
        float2 s0 = bb[row][0];               // read before scratch clobbers
        wave_fft512_c<1>(v, bb[row], lane);
        if (lane == 0)
            S0[(long long)(ch * KK + k) * 257 + a] =
                make_float2(s0.x * inv512, s0.y * inv512);
        float2* Pimg = P + (long long)(ch * KK + k) * NN;
        int prow = (a >= 1 && a <= 255) ? (a + 256) : (a == 0 ? 256 : 0);
        float2* pmain = Pimg + (long long)prow * N;
        #pragma unroll
        for (int k0 = 0; k0 < 8; ++k0) {
            int pos = kb + 64 * k0;
            float2 W = v[k0];
            pmain[pos] = make_float2(W.x * inv512, W.y * inv512);
        }
    }
}

// Fused inverse v2: PAIRED column iFFT over c + transpose + real store.
// Exact identity: Re(iFFT(G)) = iFFT(H), H[c] = (G[c]+conj(G[512-c]))/2.
// With mirror formula G[512-p] = conj(P[p]) - conj(T0)*sgn(m):
//   H[p] = P[p] - T0*sgn(m)/2  (p in [257,511]);  H[512-p] = conj(H[p]);
//   H[0] = Re(P[0]); H[256] = Re(P[256]).
// Paired rows (m even, m+1 odd) -> sgn = (+1,-1) constant. Two Hermitian
// columns pack into ONE complex iFFT: z = iFFT(H1 + i*H2), row m = Re(z),
// row m+1 = Im(z). 16 output rows / 8 FFTs per block.
__global__ __launch_bounds__(256) void k_fft_cols_inv_real(const float2* __restrict__ in,
                                                           const float2* __restrict__ T0,
                                                           float* __restrict__ out,
                                                           float scale) {
    __shared__ float tre[4896];
    __shared__ float tim[4896];
    int t = threadIdx.x;
    long long imgOff = (long long)blockIdx.y * NN;
    int b0 = blockIdx.x << 4;                       // 16 output rows per block
    {
        int xi = t & 7;                             // pair-slot (rows b0+2xi, b0+2xi+1)
        int yb = t >> 3;                            // 32 p-rows per iter
        const float2* img = in + imgOff;
        const float2* T0i = T0 + (long long)blockIdx.y * 257;
        #pragma unroll
        for (int it = 0; it < 8; ++it) {
            int p = 256 + it * 32 + yb;
            float4 q = *(const float4*)&img[(long long)p * N + b0 + 2 * xi];
            int c = p * 9 + xi;
            if (p == 256) {                         // H[256] = Re(P[256])
                tre[c] = q.x; tim[c] = q.z;
            } else {
                float2 t0 = T0i[p - 256];
                float h1x = q.x - 0.5f * t0.x, h1y = q.y - 0.5f * t0.y;  // sgn=+1
                float h2x = q.z + 0.5f * t0.x, h2y = q.w + 0.5f * t0.y;  // sgn=-1
                tre[c] = h1x - h2y; tim[c] = h1y + h2x;                  // H1 + i*H2
                int cm = (512 - p) * 9 + xi;        // conj pair -> row 512-p
                tre[cm] = h1x + h2y; tim[cm] = h2x - h1y;
            }
        }
        if (t < 8) {                                // H[0] = Re(P[0]), 16 cols
            float4 q = *(const float4*)&img[b0 + 2 * t];
            tre[t] = q.x; tim[t] = q.z;
        }
    }
    __syncthreads();
    int w = t >> 6, lane = t & 63;
    int kb = (lane >> 3) + 8 * (lane & 7);
    #pragma unroll
    for (int r = 0; r < 2; ++r) {
        int cc = (w << 1) | r;
        float2 v[8];
        #pragma unroll
        for (int e = 0; e < 8; ++e) {
            int a = (lane + 64 * e) * 9 + cc;
            v[e] = make_float2(tre[a], tim[a]);
        }
        wave_fft512<1>(v, tre, tim, lane, 9, cc);
        #pragma unroll
        for (int k0 = 0; k0 < 8; ++k0) {
            int pos = (kb + 64 * k0) * 9 + cc;
            tre[pos] = v[k0].x;                     // -> output row b0+2cc
            tim[pos] = v[k0].y;                     // -> output row b0+2cc+1
        }
    }
    __syncthreads();
    {
        int rr = t >> 4;                            // 0..15 output row in tile
        int co = t & 15;
        int slot = rr >> 1;
        const float* src = (rr & 1) ? tim : tre;
        float* orow = out + (long long)blockIdx.y * NN + (long long)(b0 + rr) * N;
        #pragma unroll
        for (int itw = 0; itw < 8; ++itw) {
            int n = itw * 64 + co * 4;
            *(float4*)&orow[n] = make_float4(src[n * 9 + slot] * scale,
                                             src[(n + 1) * 9 + slot] * scale,
                                             src[(n + 2) * 9 + slot] * scale,
                                             src[(n + 3) * 9 + slot] * scale);
        }
    }
}

// Fallback-only: in-place 512x512 complex transpose.
__global__ __launch_bounds__(256) void k_transpose_inplace(float2* __restrict__ data) {
    int ti = blockIdx.x, tj = blockIdx.y;
    if (ti > tj) return;
    float2* img = data + (long long)blockIdx.z * NN;
    __shared__ float2 ta[32][33];
    __shared__ float2 tb[32][33];
    int tx = threadIdx.x, ty = threadIdx.y;
    int r0 = ti << 5, c0 = tj << 5;
    bool diag = (ti == tj);
    #pragma unroll
    for (int kk = 0; kk < 4; ++kk) {
        int r = ty + (kk << 3);
        ta[r][tx] = img[(long long)(r0 + r) * N + (c0 + tx)];
        if (!diag) tb[r][tx] = img[(long long)(c0 + r) * N + (r0 + tx)];
    }
    __syncthreads();
    #pragma unroll
    for (int kk = 0; kk < 4; ++kk) {
        int r = ty + (kk << 3);
        img[(long long)(c0 + r) * N + (r0 + tx)] = ta[tx][r];
        if (!diag) img[(long long)(r0 + r) * N + (c0 + tx)] = tb[tx][r];
    }
}

// Fallback-only: complex rows -> iFFT -> real part.
__global__ __launch_bounds__(256) void k_fft_c2r_rows(const float2* __restrict__ in,
                                                      float* __restrict__ out, float scale) {
    __shared__ float sre[4][544];
    __shared__ float sim[4][544];
    int w = threadIdx.x >> 6, t = threadIdx.x & 63;
    long long grow = (long long)blockIdx.x * 4 + w;
    const float2* src = in + grow * N;
    float2 v[8];
    #pragma unroll
    for (int e = 0; e < 8; ++e) v[e] = src[t + 64 * e];
    wave_fft512<1>(v, sre[w], sim[w], t, 1, 0);
    float* dst = out + grow * N;
    int kb = (t >> 3) + 8 * (t & 7);
    #pragma unroll
    for (int k0 = 0; k0 < 8; ++k0) dst[kb + 64 * k0] = v[k0].x * scale;
}

// Fallback-only: standalone per-frequency solve (verified rounds 4-6).
__global__ __launch_bounds__(256) void k_solve(float2* __restrict__ Xs,
                                               const float2* __restrict__ Ys,
                                               const float* __restrict__ uu,
                                               const float* __restrict__ vv,
                                               const float* __restrict__ dd,
                                               const float* __restrict__ rhop) {
    int f = blockIdx.x * 256 + threadIdx.x;
    if (f >= FHALF) return;
    long long coffX = (long long)blockIdx.y * KK * NN;
    long long coffY = (long long)blockIdx.y * VV * NN;
    float rho = rhop[0];
    int x = f >> LOGN;
    int y = f & (N - 1);
    float wxv = (float)(x - N / 2) * (2.0f * PI_F / (float)N);
    float wyv = (float)(y - N / 2) * (2.0f * PI_F / (float)N);
    float d0 = dd[0], dlt = dd[1] - dd[0];
    float2 bacc[KK];
    float tr[KK];
    {
        float2 Yc = Ys[coffY + (long long)4 * NN + f];
        #pragma unroll
        for (int k = 0; k < KK; ++k) bacc[k] = Yc;
        tr[0] = (float)VV;
        #pragma unroll
        for (int l = 1; l < KK; ++l) tr[l] = 1.0f;
    }
    #pragma unroll
    for (int j = 0; j < 4; ++j) {
        int vp = 5 + j, vn = 3 - j;
        float s = uu[vp] * wxv + vv[vp] * wyv;
        accum_pair(bacc, tr, s, d0, dlt,
                   Ys[coffY + (long long)vp * NN + f],
                   Ys[coffY + (long long)vn * NN + f]);
    }
    #pragma unroll
    for (int k = 0; k < KK; ++k) {
        float2 Xk = Xs[coffX + (long long)k * NN + f];
        bacc[k].x += rho * Xk.x;
        bacc[k].y += rho * Xk.y;
    }
    solve_point(bacc, tr, rho);
    int xm = (N - x) & (N - 1);
    int ym = (N - y) & (N - 1);
    long long fm = (long long)xm * N + ym;
    bool conjMirror = false, zeroMirror = false;
    if (x >= 1 && x <= N / 2 - 1) {
        if (y == 0) zeroMirror = true; else conjMirror = true;
    } else if (x == N / 2 && y >= 1 && y <= N / 2 - 1) {
        conjMirror = true;
    }
    #pragma unroll
    for (int k = 0; k < KK; ++k) {
        float2* base = Xs + coffX + (long long)k * NN;
        float2 z = bacc[k];
        base[f] = z;
        if (conjMirror)      base[fm] = make_float2(z.x, -z.y);
        else if (zeroMirror) base[fm] = make_float2(0.f, 0.f);
    }
}

extern "C" void kernel_launch(void* const* d_in, const int* in_sizes, int n_in,
                              void* d_out, int out_size, void* d_ws, size_t ws_size,
                              hipStream_t stream) {
    (void)in_sizes; (void)n_in; (void)out_size;
    const float* x   = (const float*)d_in[0];
    const float* yv  = (const float*)d_in[1];
    const float* uu  = (const float*)d_in[2];
    const float* vvp = (const float*)d_in[3];
    const float* dd  = (const float*)d_in[4];
    const float* rho = (const float*)d_in[5];
    float* out = (float*)d_out;
    float2* ws = (float2*)d_ws;

    // Layout: Rt_T staging ((nx+ny)*NS*N, persists through fused solve) |
    //         P (nx images)  |  S0 table
    const float invN = 1.0f / (float)N;
    const size_t lnPer = (size_t)NS * N;
    const size_t needBatched =
        ((size_t)CCH * (KK + VV) * lnPer + (size_t)CCH * KK * NN
         + (size_t)CCH * KK * 257) * sizeof(float2);                  // ~104 MB
    const size_t needChan =
        ((size_t)(KK + VV) * lnPer + (size_t)KK * NN
         + (size_t)KK * 257) * sizeof(float2);                        // ~35 MB

    if (ws_size >= needChan) {
        bool batched = ws_size >= needBatched;
        int iters = batched ? 1 : CCH;
        int ncs   = batched ? CCH : 1;
        int nx = ncs * KK, ny = ncs * VV;
        for (int it = 0; it < iters; ++it) {
            float2* Rt = ws;                                     // staged lines
            float2* P  = ws + (size_t)(nx + ny) * lnPer;         // half-P images
            float2* S0 = P  + (size_t)nx * NN;                   // mirror table
            const float* xin = x  + (size_t)it * KK * NN;
            const float* yin = yv + (size_t)it * VV * NN;
            float* oout = out + (size_t)it * KK * NN;
            k_fft_r2c_rows_pack_T<<<(nx + ny) * 64, 256, 0, stream>>>(xin, yin, nx, Rt);
            k_fused_solve<<<dim3(257, ncs), 512, 0, stream>>>(Rt, P, S0, nx,
                                                              uu, vvp, dd, rho);
            k_fft_cols_inv_real<<<dim3(N / 16, nx), 256, 0, stream>>>(P, S0, oout, invN);
        }
    } else {
        // fallback: transpose-based pipeline, per channel (~36 MB ws)
        for (int it = 0; it < CCH; ++it) {
            float2* Xb = ws;
            float2* Yb = ws + (size_t)KK * NN;
            const float* xin = x  + (size_t)it * KK * NN;
            const float* yin = yv + (size_t)it * VV * NN;
            float* oout = out + (size_t)it * KK * NN;
            k_fft_r2c_rows<<<KK * (N / 4), 256, 0, stream>>>(xin, Xb);
            k_fft_r2c_rows<<<VV * (N / 4), 256, 0, stream>>>(yin, Yb);
            k_transpose_inplace<<<dim3(16, 16, KK), dim3(32, 8), 0, stream>>>(Xb);
            k_transpose_inplace<<<dim3(16, 16, VV), dim3(32, 8), 0, stream>>>(Yb);
            k_fft_pairswap<-1><<<KK * (N / 4), 256, 0, stream>>>(Xb, 1.0f, 0, 4);
            k_fft_pairswap<-1><<<VV * (N / 4), 256, 0, stream>>>(Yb, 1.0f, 0, 4);
            k_solve<<<dim3((FHALF + 255) / 256, 1), 256, 0, stream>>>(Xb, Yb, uu, vvp, dd, rho);
            k_fft_pairswap<1><<<KK * (N / 4), 256, 0, stream>>>(Xb, invN, 4, 0);
            k_transpose_inplace<<<dim3(16, 16, KK), dim3(32, 8), 0, stream>>>(Xb);
            k_fft_c2r_rows<<<KK * (N / 4), 256, 0, stream>>>(Xb, oout, invN);
        }
    }
}

// Round 12
// 153.159 us; speedup vs baseline: 1.1933x; 1.1933x over previous
//
#include <hip/hip_runtime.h>
#include <math.h>

// Fixed problem shapes: B=1, C=3, V=9, K=8, H=W=512
constexpr int N    = 512;
constexpr int LOGN = 9;
constexpr int NN   = N * N;                       // 262144
constexpr int CCH  = 3;
constexpr int KK   = 8;
constexpr int VV   = 9;
constexpr int FHALF = N * (N / 2) + (N / 2 + 1);  // 131329
constexpr int NS   = 257;                         // half-spectrum lines per image
constexpr int RW   = 544;                         // buf row width (= FFT scratch size)
constexpr float PI_F = 3.14159265358979323846f;

__device__ __forceinline__ float2 cmulf(float2 a, float2 b) {
    return make_float2(a.x * b.x - a.y * b.y, a.x * b.y + a.y * b.x);
}
__device__ __forceinline__ float2 cadd(float2 a, float2 b) { return make_float2(a.x + b.x, a.y + b.y); }
__device__ __forceinline__ float2 csub(float2 a, float2 b) { return make_float2(a.x - b.x, a.y - b.y); }

template<int SG>
__device__ __forceinline__ float2 cmuli(float2 z) {
    return (SG < 0) ? make_float2(z.y, -z.x) : make_float2(-z.y, z.x);
}

// 8-point DFT, natural order in/out. SG=-1 forward, +1 inverse.
template<int SG>
__device__ __forceinline__ void dft8(float2 x[8]) {
    const float c = 0.70710678118654752440f;
    float2 a0 = cadd(x[0], x[4]), a1 = cadd(x[1], x[5]);
    float2 a2 = cadd(x[2], x[6]), a3 = cadd(x[3], x[7]);
    float2 d0 = csub(x[0], x[4]), d1 = csub(x[1], x[5]);
    float2 d2 = csub(x[2], x[6]), d3 = csub(x[3], x[7]);
    float2 b0 = d0;
    float2 b1 = cmulf(d1, make_float2(c, (float)SG * c));
    float2 b2 = cmuli<SG>(d2);
    float2 b3 = cmulf(d3, make_float2(-c, (float)SG * c));
    float2 aa0 = cadd(a0, a2), aa1 = cadd(a1, a3);
    float2 ab0 = csub(a0, a2), ab1 = cmuli<SG>(csub(a1, a3));
    float2 ba0 = cadd(b0, b2), ba1 = cadd(b1, b3);
    float2 bb0 = csub(b0, b2), bb1 = cmuli<SG>(csub(b1, b3));
    x[0] = cadd(aa0, aa1); x[4] = csub(aa0, aa1);
    x[2] = cadd(ab0, ab1); x[6] = csub(ab0, ab1);
    x[1] = cadd(ba0, ba1); x[5] = csub(ba0, ba1);
    x[3] = cadd(bb0, bb1); x[7] = csub(bb0, bb1);
}

__device__ __forceinline__ void twiddle8(float2 v[8], float base) {
    float sn, cs;
    __sincosf(base, &sn, &cs);
    float2 w1 = make_float2(cs, sn);
    float2 wk = w1;
    v[1] = cmulf(v[1], wk);
    #pragma unroll
    for (int k = 2; k < 8; ++k) { wk = cmulf(wk, w1); v[k] = cmulf(v[k], wk); }
}

// Wave-level 512-pt FFT, radix-8^3 (verified round 6). One wave, 8 cx/lane.
// In: v[e]=x[t+64e]. Out: v[k0]=X[(t>>3)+8*(t&7)+64*k0]. Scratch: 544 idx slots.
template<int SG>
__device__ __forceinline__ void wave_fft512(float2 v[8], float* sre, float* sim,
                                            int t, int stride, int off) {
    int t1 = t >> 3, t0 = t & 7;
    dft8<SG>(v);
    twiddle8(v, (float)SG * (2.0f * PI_F / 512.0f) * (float)t);
    #pragma unroll
    for (int k = 0; k < 8; ++k) {
        int a = (68 * k + 8 * t1 + t0) * stride + off;
        sre[a] = v[k].x; sim[a] = v[k].y;
    }
    #pragma unroll
    for (int n = 0; n < 8; ++n) {
        int a = (68 * t1 + 8 * n + t0) * stride + off;
        v[n] = make_float2(sre[a], sim[a]);
    }
    dft8<SG>(v);
    twiddle8(v, (float)SG * (2.0f * PI_F / 64.0f) * (float)t0);
    #pragma unroll
    for (int k = 0; k < 8; ++k) {
        int a = (68 * t0 + 8 * k + t1) * stride + off;
        sre[a] = v[k].x; sim[a] = v[k].y;
    }
    #pragma unroll
    for (int n = 0; n < 8; ++n) {
        int a = (68 * n + 8 * t0 + t1) * stride + off;
        v[n] = make_float2(sre[a], sim[a]);
    }
    dft8<SG>(v);
}

// Packed r2c rows, TRANSPOSED output: each wave FFTs TWO real rows as ONE
// complex FFT, splits via Hermitian symmetry, then the block transposes its
// 8 rows x 257 half-spectrum cols in LDS and stores column-major:
// outT[img][s][row], s = (p==0) ? 256 : p-256 for p in {0} U [256,511].
// LDS: FFT scratch (4x544 re/im) aliased with the 257x9-padded tile.
__global__ __launch_bounds__(256) void k_fft_r2c_rows_pack_T(const float* __restrict__ inx,
                                                             const float* __restrict__ iny,
                                                             int nximg,
                                                             float2* __restrict__ outT) {
    __shared__ float ure[2313];       // max(4*544, 257*9) = 2313
    __shared__ float uim[2313];
    int w = threadIdx.x >> 6, t = threadIdx.x & 63;
    int blk = blockIdx.x;             // 64 blocks per image, 8 rows per block
    int img = blk >> 6;
    int rowbase = (blk & 63) << 3;
    long long row0 = (long long)blk * 8 + 2 * w;   // global row (pairs never straddle)
    long long xrows = (long long)nximg * N;
    const float* src0 = (row0 < xrows) ? (inx + row0 * N)
                                       : (iny + (row0 - xrows) * N);
    const float* src1 = src0 + N;
    float* sre = ure + w * 544;
    float* sim = uim + w * 544;
    float2 v[8];
    #pragma unroll
    for (int e = 0; e < 8; ++e) v[e] = make_float2(src0[t + 64 * e], src1[t + 64 * e]);
    wave_fft512<-1>(v, sre, sim, t, 1, 0);
    int kb = (t >> 3) + 8 * (t & 7);
    #pragma unroll
    for (int k0 = 0; k0 < 8; ++k0) {          // full spectrum for mirror reads
        int p = kb + 64 * k0;
        sre[p] = v[k0].x; sim[p] = v[k0].y;
    }
    float2 r0v[4], r1v[4];
    #pragma unroll
    for (int k0 = 4; k0 < 8; ++k0) {
        int p  = kb + 64 * k0;                // 256..511
        int mp = 512 - p;                     // 1..256
        float zmx = sre[mp], zmy = sim[mp];
        float2 Zp = v[k0];
        r0v[k0 - 4] = make_float2(0.5f * (Zp.x + zmx), 0.5f * (Zp.y - zmy));
        r1v[k0 - 4] = make_float2(0.5f * (Zp.y + zmy), 0.5f * (zmx - Zp.x));
    }
    float2 z0 = v[0];                          // lane 0 holds X[0]
    __syncthreads();                           // scratch reads done; alias as tile
    #pragma unroll
    for (int k0 = 0; k0 < 4; ++k0) {
        int s = kb + 64 * k0;                  // p-256 in [0,255]
        ure[s * 9 + 2 * w]     = r0v[k0].x; uim[s * 9 + 2 * w]     = r0v[k0].y;
        ure[s * 9 + 2 * w + 1] = r1v[k0].x; uim[s * 9 + 2 * w + 1] = r1v[k0].y;
    }
    if (t == 0) {                              // p = 0 -> slot 256
        ure[256 * 9 + 2 * w]     = z0.x; uim[256 * 9 + 2 * w]     = 0.0f;
        ure[256 * 9 + 2 * w + 1] = z0.y; uim[256 * 9 + 2 * w + 1] = 0.0f;
    }
    __syncthreads();
    float2* dst = outT + (long long)img * ((long long)NS * N);
    int tt = threadIdx.x;
    int r2 = (tt & 3) << 1;                    // even row-pair -> float4 store
    #pragma unroll
    for (int j = 0; j < 4; ++j) {
        int s = j * 64 + (tt >> 2);
        *(float4*)&dst[s * N + rowbase + r2] =
            make_float4(ure[s * 9 + r2],     uim[s * 9 + r2],
                        ure[s * 9 + r2 + 1], uim[s * 9 + r2 + 1]);
    }
    if (tt < 4) {
        int r2b = tt << 1;
        *(float4*)&dst[256 * N + rowbase + r2b] =
            make_float4(ure[256 * 9 + r2b],     uim[256 * 9 + r2b],
                        ure[256 * 9 + r2b + 1], uim[256 * 9 + r2b + 1]);
    }
}

// Fallback-only: full r2c rows.
__global__ __launch_bounds__(256) void k_fft_r2c_rows(const float* __restrict__ in,
                                                      float2* __restrict__ out) {
    __shared__ float sre[4][544];
    __shared__ float sim[4][544];
    int w = threadIdx.x >> 6, t = threadIdx.x & 63;
    long long grow = (long long)blockIdx.x * 4 + w;
    const float* src = in + grow * N;
    float2 v[8];
    #pragma unroll
    for (int e = 0; e < 8; ++e) v[e] = make_float2(src[t + 64 * e], 0.0f);
    wave_fft512<-1>(v, sre[w], sim[w], t, 1, 0);
    float2* dst = out + grow * N;
    int kb = (t >> 3) + 8 * (t & 7);
    #pragma unroll
    for (int k0 = 0; k0 < 8; ++k0) dst[kb + 64 * k0] = v[k0];
}

// Fallback-only: in-place row FFT with r<->r^256 swap; lex/sex in units of 64.
template<int SG>
__global__ __launch_bounds__(256) void k_fft_pairswap(float2* __restrict__ data,
                                                      float scale, int lex, int sex) {
    __shared__ float sre[4][544];
    __shared__ float sim[4][544];
    int w = threadIdx.x >> 6, t = threadIdx.x & 63;
    int b = blockIdx.x;
    long long imgBase = (long long)(b >> 7) * NN;
    int pa = (b & 127) << 1;
    int rowg = pa + (w & 1) + ((w >> 1) << 8);
    const float2* src = data + imgBase + (long long)rowg * N;
    float2 v[8];
    #pragma unroll
    for (int e = 0; e < 8; ++e) v[e] = src[t + 64 * (e ^ lex)];
    __syncthreads();
    wave_fft512<SG>(v, sre[w], sim[w], t, 1, 0);
    float2* dst = data + imgBase + (long long)(rowg ^ 256) * N;
    int kb = (t >> 3) + 8 * (t & 7);
    #pragma unroll
    for (int k0 = 0; k0 < 8; ++k0) {
        float2 z = v[k0];
        dst[kb + 64 * (k0 ^ sex)] = make_float2(z.x * scale, z.y * scale);
    }
}

// ---- solve helpers (arithmetic verbatim from the verified k_solve) ----
__device__ __forceinline__ void accum_pair(float2 bacc[KK], float tr[KK], float s,
                                           float d0, float dlt, float2 Yp, float2 Yn) {
    float2 Sp = make_float2(Yp.x + Yn.x, Yp.y + Yn.y);
    float2 Dm = make_float2(Yp.x - Yn.x, Yp.y - Yn.y);
    float sn, cs;
    __sincosf(s * d0, &sn, &cs);  float2 p = make_float2(cs, sn);
    __sincosf(s * dlt, &sn, &cs); float2 q = make_float2(cs, sn);
    float2 w = q;
    #pragma unroll
    for (int k = 0; k < KK; ++k) {
        bacc[k].x += p.x * Sp.x + p.y * Dm.y;
        bacc[k].y += p.x * Sp.y - p.y * Dm.x;
        if (k < KK - 1) {
            p = cmulf(p, q);
            tr[k + 1] += 2.0f * w.x;
            w = cmulf(w, q);
        }
    }
}

__device__ __forceinline__ void solve_point(float2 bacc[KK], float tr[KK], float rho) {
    float diag = tr[0] + rho;
    float L[36], Li[KK];
    #pragma unroll
    for (int j = 0; j < KK; ++j) {
        float acc = diag;
        #pragma unroll
        for (int t = 0; t < j; ++t) { float l = L[(j * (j - 1)) / 2 + t]; acc -= l * l; }
        float dj = sqrtf(acc);
        float inv = 1.0f / dj;
        Li[j] = inv;
        #pragma unroll
        for (int i = j + 1; i < KK; ++i) {
            float a = tr[i - j];
            #pragma unroll
            for (int t = 0; t < j; ++t)
                a -= L[(i * (i - 1)) / 2 + t] * L[(j * (j - 1)) / 2 + t];
            L[(i * (i - 1)) / 2 + j] = a * inv;
        }
    }
    #pragma unroll
    for (int i = 0; i < KK; ++i) {
        float2 a = bacc[i];
        #pragma unroll
        for (int t = 0; t < i; ++t) {
            float l = L[(i * (i - 1)) / 2 + t];
            a.x -= l * bacc[t].x;
            a.y -= l * bacc[t].y;
        }
        bacc[i] = make_float2(a.x * Li[i], a.y * Li[i]);
    }
    #pragma unroll
    for (int i = KK - 1; i >= 0; --i) {
        float2 a = bacc[i];
        #pragma unroll
        for (int t = i + 1; t < KK; ++t) {
            float l = L[(t * (t - 1)) / 2 + i];
            a.x -= l * bacc[t].x;
            a.y -= l * bacc[t].y;
        }
        bacc[i] = make_float2(a.x * Li[i], a.y * Li[i]);
    }
}

// FUSED v4 (reverted best): ONE merged FFT phase (17 lines: Y[w]->row w,
// X[w]->row 9+w, wave 0 also Y[8]->row 8), then accum+solve, then inverse
// iFFT.  Barriers: 2.  LDS: 17 rows x 544 re/im = 74 KB -> 2 blocks/CU.
// 512 threads; thread t owns spectral point b=t.
// NOTE (round 11 post-mortem): float2/b64 LDS variant caused a regalloc
// collapse (VGPR 64 + ~90 MB scratch spill, +29 us) — keep b32 re/im split.
__global__ __launch_bounds__(512, 4) void k_fused_solve(const float2* __restrict__ Rt,
                                                        float2* __restrict__ P,
                                                        float2* __restrict__ S0,
                                                        int nximg,
                                                        const float* __restrict__ uu,
                                                        const float* __restrict__ vvp,
                                                        const float* __restrict__ dd,
                                                        const float* __restrict__ rhop) {
    __shared__ float bre[KK + VV][RW];   // rows 0..8: Y, rows 9..16: X/solution
    __shared__ float bim[KK + VV][RW];   // 2 * 17 * 544 * 4B = 74.0 KB
    int a  = blockIdx.x;                 // 0..256
    int ch = blockIdx.y;
    int t  = threadIdx.x;                // 0..511
    int w = t >> 6, lane = t & 63;
    int kb = (lane >> 3) + 8 * (lane & 7);
    const long long LN = (long long)NS * N;

    // FFT phase: issue Y[w] + X[w] loads together, FFT both (X latency hides
    // under Y's FFT).  Wave 0 additionally handles Y[8].
    {
        int ybase = nximg + ch * VV;
        float2 fvY[8], fvX[8];
        const float2* srcY = Rt + (long long)(ybase + w) * LN + (long long)a * N;
        const float2* srcX = Rt + (long long)(ch * KK + w) * LN + (long long)a * N;
        #pragma unroll
        for (int e = 0; e < 8; ++e) fvY[e] = srcY[lane + 64 * e];
        #pragma unroll
        for (int e = 0; e < 8; ++e) fvX[e] = srcX[lane + 64 * e];
        wave_fft512<-1>(fvY, bre[w], bim[w], lane, 1, 0);
        #pragma unroll
        for (int k0 = 0; k0 < 8; ++k0) {
            int pos = kb + 64 * (k0 ^ 4);            // fold the ky-roll
            bre[w][pos] = fvY[k0].x; bim[w][pos] = fvY[k0].y;
        }
        wave_fft512<-1>(fvX, bre[9 + w], bim[9 + w], lane, 1, 0);
        #pragma unroll
        for (int k0 = 0; k0 < 8; ++k0) {
            int pos = kb + 64 * (k0 ^ 4);
            bre[9 + w][pos] = fvX[k0].x; bim[9 + w][pos] = fvX[k0].y;
        }
        if (w == 0) {                                // 17th line: Y[8]
            const float2* src8 = Rt + (long long)(ybase + 8) * LN + (long long)a * N;
            float2 fv8[8];
            #pragma unroll
            for (int e = 0; e < 8; ++e) fv8[e] = src8[lane + 64 * e];
            wave_fft512<-1>(fv8, bre[8], bim[8], lane, 1, 0);
            #pragma unroll
            for (int k0 = 0; k0 < 8; ++k0) {
                int pos = kb + 64 * (k0 ^ 4);
                bre[8][pos] = fv8[k0].x; bim[8][pos] = fv8[k0].y;
            }
        }
    }
    __syncthreads();

    // Solve phase: accum RHS + Toeplitz traces, add rho*X, Cholesky solve,
    // write solutions back to rows 9..16 (thread t owns slot t).
    float rho = rhop[0];
    float d0 = dd[0], dlt = dd[1] - dd[0];
    const float C = 2.0f * PI_F / (float)N;
    float wxv = (float)(a - 256) * C;
    float wy  = (float)(t - 256) * C;
    float2 bacc[KK];
    float tr[KK];
    {
        float2 yc = make_float2(bre[4][t], bim[4][t]);
        #pragma unroll
        for (int k = 0; k < KK; ++k) bacc[k] = yc;
        tr[0] = (float)VV;
        #pragma unroll
        for (int l = 1; l < KK; ++l) tr[l] = 1.0f;
    }
    #pragma unroll
    for (int j = 0; j < 4; ++j) {
        int vp = 5 + j, vn = 3 - j;
        accum_pair(bacc, tr, uu[vp] * wxv + vvp[vp] * wy, d0, dlt,
                   make_float2(bre[vp][t], bim[vp][t]),
                   make_float2(bre[vn][t], bim[vn][t]));
    }
    #pragma unroll
    for (int k = 0; k < KK; ++k) {
        bacc[k].x += rho * bre[9 + k][t];
        bacc[k].y += rho * bim[9 + k][t];
    }
    solve_point(bacc, tr, rho);
    #pragma unroll
    for (int k = 0; k < KK; ++k) {
        bre[9 + k][t] = bacc[k].x;
        bim[9 + k][t] = bacc[k].y;
    }
    __syncthreads();

    // Inverse phase: iFFT (wave w -> k=w, row 9+w) + half-P store.
    // a==256 self-mirror folded into the read: g[idx>=257] = conj(g[512-idx]).
    {
        const float inv512 = 1.0f / 512.0f;
        int k = w;
        int row = 9 + w;
        bool selfm = (a == 256);              // uniform per block
        float2 v[8];
        #pragma unroll
        for (int e = 0; e < 8; ++e) {
            int idx = (lane + 64 * e) ^ 256;  // fold the b-roll into the load
            if (selfm && idx >= 257) {
                int bs = 512 - idx;
                v[e] = make_float2(bre[row][bs], -bim[row][bs]);
            } else {
                v[e] = make_float2(bre[row][idx], bim[row][idx]);
            }
        }
        float s0x = bre[row][0], s0y = bim[row][0]; // read before scratch clobbers
        wave_fft512<1>(v, bre[row], bim[row], lane, 1, 0);
        if (lane == 0)
            S0[(long long)(ch * KK + k) * 257 + a] =
                make_float2(s0x * inv512, s0y * inv512);
        float2* Pimg = P + (long long)(ch * KK + k) * NN;
        int prow = (a >= 1 && a <= 255) ? (a + 256) : (a == 0 ? 256 : 0);
        float2* pmain = Pimg + (long long)prow * N;
        #pragma unroll
        for (int k0 = 0; k0 < 8; ++k0) {
            int pos = kb + 64 * k0;
            float2 W = v[k0];
            pmain[pos] = make_float2(W.x * inv512, W.y * inv512);
        }
    }
}

// Fused inverse v2: PAIRED column iFFT over c + transpose + real store.
// Exact identity: Re(iFFT(G)) = iFFT(H), H[c] = (G[c]+conj(G[512-c]))/2.
// With mirror formula G[512-p] = conj(P[p]) - conj(T0)*sgn(m):
//   H[p] = P[p] - T0*sgn(m)/2  (p in [257,511]);  H[512-p] = conj(H[p]);
//   H[0] = Re(P[0]); H[256] = Re(P[256]).
// Paired rows (m even, m+1 odd) -> sgn = (+1,-1) constant. Two Hermitian
// columns pack into ONE complex iFFT: z = iFFT(H1 + i*H2), row m = Re(z),
// row m+1 = Im(z). 16 output rows / 8 FFTs per block.
__global__ __launch_bounds__(256) void k_fft_cols_inv_real(const float2* __restrict__ in,
                                                           const float2* __restrict__ T0,
                                                           float* __restrict__ out,
                                                           float scale) {
    __shared__ float tre[4896];
    __shared__ float tim[4896];
    int t = threadIdx.x;
    long long imgOff = (long long)blockIdx.y * NN;
    int b0 = blockIdx.x << 4;                       // 16 output rows per block
    {
        int xi = t & 7;                             // pair-slot (rows b0+2xi, b0+2xi+1)
        int yb = t >> 3;                            // 32 p-rows per iter
        const float2* img = in + imgOff;
        const float2* T0i = T0 + (long long)blockIdx.y * 257;
        #pragma unroll
        for (int it = 0; it < 8; ++it) {
            int p = 256 + it * 32 + yb;
            float4 q = *(const float4*)&img[(long long)p * N + b0 + 2 * xi];
            int c = p * 9 + xi;
            if (p == 256) {                         // H[256] = Re(P[256])
                tre[c] = q.x; tim[c] = q.z;
            } else {
                float2 t0 = T0i[p - 256];
                float h1x = q.x - 0.5f * t0.x, h1y = q.y - 0.5f * t0.y;  // sgn=+1
                float h2x = q.z + 0.5f * t0.x, h2y = q.w + 0.5f * t0.y;  // sgn=-1
                tre[c] = h1x - h2y; tim[c] = h1y + h2x;                  // H1 + i*H2
                int cm = (512 - p) * 9 + xi;        // conj pair -> row 512-p
                tre[cm] = h1x + h2y; tim[cm] = h2x - h1y;
            }
        }
        if (t < 8) {                                // H[0] = Re(P[0]), 16 cols
            float4 q = *(const float4*)&img[b0 + 2 * t];
            tre[t] = q.x; tim[t] = q.z;
        }
    }
    __syncthreads();
    int w = t >> 6, lane = t & 63;
    int kb = (lane >> 3) + 8 * (lane & 7);
    #pragma unroll
    for (int r = 0; r < 2; ++r) {
        int cc = (w << 1) | r;
        float2 v[8];
        #pragma unroll
        for (int e = 0; e < 8; ++e) {
            int a = (lane + 64 * e) * 9 + cc;
            v[e] = make_float2(tre[a], tim[a]);
        }
        wave_fft512<1>(v, tre, tim, lane, 9, cc);
        #pragma unroll
        for (int k0 = 0; k0 < 8; ++k0) {
            int pos = (kb + 64 * k0) * 9 + cc;
            tre[pos] = v[k0].x;                     // -> output row b0+2cc
            tim[pos] = v[k0].y;                     // -> output row b0+2cc+1
        }
    }
    __syncthreads();
    {
        int rr = t >> 4;                            // 0..15 output row in tile
        int co = t & 15;
        int slot = rr >> 1;
        const float* src = (rr & 1) ? tim : tre;
        float* orow = out + (long long)blockIdx.y * NN + (long long)(b0 + rr) * N;
        #pragma unroll
        for (int itw = 0; itw < 8; ++itw) {
            int n = itw * 64 + co * 4;
            *(float4*)&orow[n] = make_float4(src[n * 9 + slot] * scale,
                                             src[(n + 1) * 9 + slot] * scale,
                                             src[(n + 2) * 9 + slot] * scale,
                                             src[(n + 3) * 9 + slot] * scale);
        }
    }
}

// Fallback-only: in-place 512x512 complex transpose.
__global__ __launch_bounds__(256) void k_transpose_inplace(float2* __restrict__ data) {
    int ti = blockIdx.x, tj = blockIdx.y;
    if (ti > tj) return;
    float2* img = data + (long long)blockIdx.z * NN;
    __shared__ float2 ta[32][33];
    __shared__ float2 tb[32][33];
    int tx = threadIdx.x, ty = threadIdx.y;
    int r0 = ti << 5, c0 = tj << 5;
    bool diag = (ti == tj);
    #pragma unroll
    for (int kk = 0; kk < 4; ++kk) {
        int r = ty + (kk << 3);
        ta[r][tx] = img[(long long)(r0 + r) * N + (c0 + tx)];
        if (!diag) tb[r][tx] = img[(long long)(c0 + r) * N + (r0 + tx)];
    }
    __syncthreads();
    #pragma unroll
    for (int kk = 0; kk < 4; ++kk) {
        int r = ty + (kk << 3);
        img[(long long)(c0 + r) * N + (r0 + tx)] = ta[tx][r];
        if (!diag) img[(long long)(r0 + r) * N + (c0 + tx)] = tb[tx][r];
    }
}

// Fallback-only: complex rows -> iFFT -> real part.
__global__ __launch_bounds__(256) void k_fft_c2r_rows(const float2* __restrict__ in,
                                                      float* __restrict__ out, float scale) {
    __shared__ float sre[4][544];
    __shared__ float sim[4][544];
    int w = threadIdx.x >> 6, t = threadIdx.x & 63;
    long long grow = (long long)blockIdx.x * 4 + w;
    const float2* src = in + grow * N;
    float2 v[8];
    #pragma unroll
    for (int e = 0; e < 8; ++e) v[e] = src[t + 64 * e];
    wave_fft512<1>(v, sre[w], sim[w], t, 1, 0);
    float* dst = out + grow * N;
    int kb = (t >> 3) + 8 * (t & 7);
    #pragma unroll
    for (int k0 = 0; k0 < 8; ++k0) dst[kb + 64 * k0] = v[k0].x * scale;
}

// Fallback-only: standalone per-frequency solve (verified rounds 4-6).
__global__ __launch_bounds__(256) void k_solve(float2* __restrict__ Xs,
                                               const float2* __restrict__ Ys,
                                               const float* __restrict__ uu,
                                               const float* __restrict__ vv,
                                               const float* __restrict__ dd,
                                               const float* __restrict__ rhop) {
    int f = blockIdx.x * 256 + threadIdx.x;
    if (f >= FHALF) return;
    long long coffX = (long long)blockIdx.y * KK * NN;
    long long coffY = (long long)blockIdx.y * VV * NN;
    float rho = rhop[0];
    int x = f >> LOGN;
    int y = f & (N - 1);
    float wxv = (float)(x - N / 2) * (2.0f * PI_F / (float)N);
    float wyv = (float)(y - N / 2) * (2.0f * PI_F / (float)N);
    float d0 = dd[0], dlt = dd[1] - dd[0];
    float2 bacc[KK];
    float tr[KK];
    {
        float2 Yc = Ys[coffY + (long long)4 * NN + f];
        #pragma unroll
        for (int k = 0; k < KK; ++k) bacc[k] = Yc;
        tr[0] = (float)VV;
        #pragma unroll
        for (int l = 1; l < KK; ++l) tr[l] = 1.0f;
    }
    #pragma unroll
    for (int j = 0; j < 4; ++j) {
        int vp = 5 + j, vn = 3 - j;
        float s = uu[vp] * wxv + vv[vp] * wyv;
        accum_pair(bacc, tr, s, d0, dlt,
                   Ys[coffY + (long long)vp * NN + f],
                   Ys[coffY + (long long)vn * NN + f]);
    }
    #pragma unroll
    for (int k = 0; k < KK; ++k) {
        float2 Xk = Xs[coffX + (long long)k * NN + f];
        bacc[k].x += rho * Xk.x;
        bacc[k].y += rho * Xk.y;
    }
    solve_point(bacc, tr, rho);
    int xm = (N - x) & (N - 1);
    int ym = (N - y) & (N - 1);
    long long fm = (long long)xm * N + ym;
    bool conjMirror = false, zeroMirror = false;
    if (x >= 1 && x <= N / 2 - 1) {
        if (y == 0) zeroMirror = true; else conjMirror = true;
    } else if (x == N / 2 && y >= 1 && y <= N / 2 - 1) {
        conjMirror = true;
    }
    #pragma unroll
    for (int k = 0; k < KK; ++k) {
        float2* base = Xs + coffX + (long long)k * NN;
        float2 z = bacc[k];
        base[f] = z;
        if (conjMirror)      base[fm] = make_float2(z.x, -z.y);
        else if (zeroMirror) base[fm] = make_float2(0.f, 0.f);
    }
}

extern "C" void kernel_launch(void* const* d_in, const int* in_sizes, int n_in,
                              void* d_out, int out_size, void* d_ws, size_t ws_size,
                              hipStream_t stream) {
    (void)in_sizes; (void)n_in; (void)out_size;
    const float* x   = (const float*)d_in[0];
    const float* yv  = (const float*)d_in[1];
    const float* uu  = (const float*)d_in[2];
    const float* vvp = (const float*)d_in[3];
    const float* dd  = (const float*)d_in[4];
    const float* rho = (const float*)d_in[5];
    float* out = (float*)d_out;
    float2* ws = (float2*)d_ws;

    // Layout: Rt_T staging ((nx+ny)*NS*N, persists through fused solve) |
    //         P (nx images)  |  S0 table
    const float invN = 1.0f / (float)N;
    const size_t lnPer = (size_t)NS * N;
    const size_t needBatched =
        ((size_t)CCH * (KK + VV) * lnPer + (size_t)CCH * KK * NN
         + (size_t)CCH * KK * 257) * sizeof(float2);                  // ~104 MB
    const size_t needChan =
        ((size_t)(KK + VV) * lnPer + (size_t)KK * NN
         + (size_t)KK * 257) * sizeof(float2);                        // ~35 MB

    if (ws_size >= needChan) {
        bool batched = ws_size >= needBatched;
        int iters = batched ? 1 : CCH;
        int ncs   = batched ? CCH : 1;
        int nx = ncs * KK, ny = ncs * VV;
        for (int it = 0; it < iters; ++it) {
            float2* Rt = ws;                                     // staged lines
            float2* P  = ws + (size_t)(nx + ny) * lnPer;         // half-P images
            float2* S0 = P  + (size_t)nx * NN;                   // mirror table
            const float* xin = x  + (size_t)it * KK * NN;
            const float* yin = yv + (size_t)it * VV * NN;
            float* oout = out + (size_t)it * KK * NN;
            k_fft_r2c_rows_pack_T<<<(nx + ny) * 64, 256, 0, stream>>>(xin, yin, nx, Rt);
            k_fused_solve<<<dim3(257, ncs), 512, 0, stream>>>(Rt, P, S0, nx,
                                                              uu, vvp, dd, rho);
            k_fft_cols_inv_real<<<dim3(N / 16, nx), 256, 0, stream>>>(P, S0, oout, invN);
        }
    } else {
        // fallback: transpose-based pipeline, per channel (~36 MB ws)
        for (int it = 0; it < CCH; ++it) {
            float2* Xb = ws;
            float2* Yb = ws + (size_t)KK * NN;
            const float* xin = x  + (size_t)it * KK * NN;
            const float* yin = yv + (size_t)it * VV * NN;
            float* oout = out + (size_t)it * KK * NN;
            k_fft_r2c_rows<<<KK * (N / 4), 256, 0, stream>>>(xin, Xb);
            k_fft_r2c_rows<<<VV * (N / 4), 256, 0, stream>>>(yin, Yb);
            k_transpose_inplace<<<dim3(16, 16, KK), dim3(32, 8), 0, stream>>>(Xb);
            k_transpose_inplace<<<dim3(16, 16, VV), dim3(32, 8), 0, stream>>>(Yb);
            k_fft_pairswap<-1><<<KK * (N / 4), 256, 0, stream>>>(Xb, 1.0f, 0, 4);
            k_fft_pairswap<-1><<<VV * (N / 4), 256, 0, stream>>>(Yb, 1.0f, 0, 4);
            k_solve<<<dim3((FHALF + 255) / 256, 1), 256, 0, stream>>>(Xb, Yb, uu, vvp, dd, rho);
            k_fft_pairswap<1><<<KK * (N / 4), 256, 0, stream>>>(Xb, invN, 4, 0);
            k_transpose_inplace<<<dim3(16, 16, KK), dim3(32, 8), 0, stream>>>(Xb);
            k_fft_c2r_rows<<<KK * (N / 4), 256, 0, stream>>>(Xb, oout, invN);
        }
    }
}